// Round 10
// baseline (273.742 us; speedup 1.0000x reference)
//
#include <hip/hip_runtime.h>
#include <math.h>

// Problem constants
constexpr int C_ = 128, A_ = 64, K_ = 24, S_ = 4;
constexpr int NATOM = C_ * A_;    // 8192
constexpr int FAEV = 384;         // 64 radial + 320 angular
constexpr float RCR = 5.2f, RCA = 3.5f;
constexpr float PI_F = 3.14159265358979323846f;
// exp folded to exp2: exp(-eta*x^2) = exp2(K * x^2)
constexpr float K_A2 = -8.0f  * 1.44269504f;          // angular, on (hs - shfa)^2
constexpr float K_R2 = -64.0f * 1.44269504f;          // radial, on (d/2 - shfr/2)^2
constexpr float SQRT095 = 0.974679434f;               // sqrt(0.95) folded into unit vectors
constexpr float SQRT2   = 1.41421356237f;             // folded into fca (gives the 2* factor)

// ---------------- kernel 1: setup — species-sorted atom list + zero out ----------------
__global__ __launch_bounds__(1024) void setup_kernel(const int* __restrict__ elem,
                                                     int* __restrict__ cnt,
                                                     int* __restrict__ glist,
                                                     float* __restrict__ out) {
    __shared__ int cnt_s[S_];
    const int t = threadIdx.x;
    const int lane = t & 63;
    if (t < S_) cnt_s[t] = 0;
    if (t < C_) out[t] = 0.0f;
    __syncthreads();
    for (int a = t; a < NATOM; a += 1024) {
        int sp = elem[a];
        unsigned long long lt = (lane == 0) ? 0ULL : ((~0ULL) >> (64 - lane));
        int pos = 0;
        #pragma unroll
        for (int q = 0; q < S_; ++q) {
            unsigned long long m = __ballot(sp == q);
            int cw = (int)__popcll(m);
            int b = 0;
            if (lane == 0 && cw) b = atomicAdd(&cnt_s[q], cw);
            b = __shfl(b, 0);
            if (sp == q) pos = b + (int)__popcll(m & lt);
        }
        glist[sp * NATOM + pos] = a;
    }
    __syncthreads();
    if (t < S_) cnt[t] = cnt_s[t];
}

// ---------------- kernel 2: fused AEV + MLP ----------------
// 1024 blocks x 512 threads. Block = 8 same-species atoms (from glist).
// Phase A: wave w computes atom w's AEV into LDS. Phase B: MLP from LDS.
__global__ __launch_bounds__(512, 8) void fused_kernel(const int* __restrict__ elem,
                                                       const int* __restrict__ nbr,
                                                       const float* __restrict__ dist,
                                                       const float* __restrict__ dv,
                                                       const int* __restrict__ cnt,
                                                       const int* __restrict__ glist,
                                                       const float* __restrict__ W1, const float* __restrict__ b1,
                                                       const float* __restrict__ W2, const float* __restrict__ b2,
                                                       const float* __restrict__ W3, const float* __restrict__ b3,
                                                       const float* __restrict__ W4, const float* __restrict__ b4,
                                                       float* __restrict__ out) {
    const int s     = blockIdx.x >> 8;          // species (4 x 256 blocks)
    const int tile0 = blockIdx.x & 255;
    const int t     = threadIdx.x;
    const int w     = t >> 6;                   // wave = atom slot 0..7
    const int lane  = t & 63;
    const int cntS  = cnt[s];

    __shared__ float4        u4_s[8][K_];       // {ux*q, uy*q, uz*q, d/2}, q = sqrt(0.95)/d
    __shared__ float         fcr_s[8][K_];
    __shared__ float         fca_s[8][K_];      // premultiplied by sqrt(2)
    __shared__ int           spec_s[8][K_];
    __shared__ unsigned char bidx_s[8][S_][K_];
    __shared__ int           nsp_s[8][S_];
    __shared__ int           atom_sh[8];
    __shared__ __attribute__((aligned(16))) float aev_s[8][FAEV];  // overlays h2(8x128)+h3(8x96)
    __shared__ __attribute__((aligned(16))) float h1_s[8][160];
    float (*h2_s)[128] = (float(*)[128])&aev_s[0][0];
    float (*h3_s)[96]  = (float(*)[96])(&aev_s[0][0] + 8 * 128);

    const float* W1s = W1 + s * (FAEV * 160);
    const float* b1s = b1 + s * 160;
    const float* W2s = W2 + s * (160 * 128);
    const float* b2s = b2 + s * 128;
    const float* W3s = W3 + s * (128 * 96);
    const float* b3s = b3 + s * 96;
    const float* W4s = W4 + s * 96;
    const float  bb4 = b4[s];

    // per-lane angular constants
    const int lane32 = lane & 31;
    const int par    = lane >> 5;
    const int zz = lane32 >> 2, yy = lane32 & 3;
    const float cz2 = 0.5f * __cosf(((float)zz + 0.5f) * (PI_F / 8.0f));
    const float sz2 = 0.5f * __sinf(((float)zz + 0.5f) * (PI_F / 8.0f));
    const float shfa_l = 0.9f + 0.65f * (float)yy;

    for (int tile = tile0; tile * 8 < cntS; tile += 256) {
        const int g = tile * 8 + w;
        const int atomAbs = (g < cntS) ? glist[s * NATOM + g] : -1;
        if (lane == 0) atom_sh[w] = atomAbs;

        // ---- phase A1: neighbor load + precompute (lanes 0..23 of each wave) ----
        if (atomAbs >= 0 && lane < K_) {
            int base = atomAbs * K_ + lane;
            int c    = atomAbs >> 6;
            int nb   = nbr[base];
            float d  = dist[base];
            float inv = __builtin_amdgcn_rcpf(d) * SQRT095;
            float4 u;
            u.x = dv[base * 3 + 0] * inv;
            u.y = dv[base * 3 + 1] * inv;
            u.z = dv[base * 3 + 2] * inv;
            u.w = 0.5f * d;
            u4_s[w][lane]  = u;
            spec_s[w][lane] = elem[(c << 6) + nb];
            fcr_s[w][lane] = (d < RCR) ? (0.5f * __cosf(PI_F * d * (1.0f / RCR)) + 0.5f) : 0.0f;
            fca_s[w][lane] = (d < RCA) ? (SQRT2 * (0.5f * __cosf(PI_F * d * (1.0f / RCA)) + 0.5f)) : 0.0f;
        }
        __syncthreads();

        // ---- phase A2: bucket active neighbors by species (lanes 0..3 of each wave) ----
        if (atomAbs >= 0 && lane < S_) {
            int n = 0;
            #pragma unroll
            for (int k = 0; k < K_; ++k)
                if (fca_s[w][k] > 0.0f && spec_s[w][k] == lane)
                    bidx_s[w][lane][n++] = (unsigned char)k;
            nsp_s[w][lane] = n;
        }
        __syncthreads();

        // ---- phase A3: radial + angular AEV (full wave per atom) ----
        if (atomAbs >= 0) {
            // radial: lane = sp*16 + shell
            {
                const int   spg   = lane >> 4;
                const float shfrh = 0.5f * (0.9f + 0.26875f * (float)(lane & 15));
                float acc = 0.0f;
                #pragma unroll
                for (int k = 0; k < K_; ++k) {
                    float hd = u4_s[w][k].w;
                    float df = hd - shfrh;
                    float term = 0.25f * exp2f(df * df * K_R2) * fcr_s[w][k];
                    if (spec_s[w][k] == spg) acc += term;
                }
                aev_s[w][lane] = acc;
            }
            // angular: 10 species-pair segments; halves = even/odd pairs of the stream
            auto pair_term = [&](int j, int k2) -> float {
                float4 u1 = u4_s[w][j], u2 = u4_s[w][k2];
                float ca = u1.x * u2.x + u1.y * u2.y + u1.z * u2.z;   // = 0.95*cos
                float sa = sqrtf(1.0f - ca * ca);
                float dd = (u1.w + u2.w) - shfa_l;
                float f2 = exp2f(dd * dd * K_A2);
                float x  = 0.5f + ca * cz2 + sa * sz2;
                float x2 = x * x, x4 = x2 * x2, x8 = x4 * x4, x16 = x8 * x8;
                float tc = fca_s[w][j] * fca_s[w][k2];                // = 2*fc1*fc2
                return (x16 * x16) * (f2 * tc);
            };
            #pragma unroll
            for (int spa = 0; spa < 4; ++spa) {
                #pragma unroll
                for (int spb = spa; spb < 4; ++spb) {
                    const int pidx = spa * (9 - spa) / 2 + (spb - spa);
                    const int na  = nsp_s[w][spa];
                    const int nb2 = nsp_s[w][spb];
                    float acc = 0.0f;
                    if (spa == spb) {
                        int jj = 0, kk = 1 + par;
                        while (jj < na - 1 && kk >= na) { int ov = kk - na; ++jj; kk = jj + 1 + ov; }
                        while (jj < na - 1) {
                            acc += pair_term((int)bidx_s[w][spa][jj], (int)bidx_s[w][spa][kk]);
                            kk += 2;
                            while (jj < na - 1 && kk >= na) { int ov = kk - na; ++jj; kk = jj + 1 + ov; }
                        }
                    } else {
                        int jj = 0, kk = par;
                        while (jj < na && kk >= nb2) { kk -= nb2; ++jj; }
                        while (jj < na) {
                            acc += pair_term((int)bidx_s[w][spa][jj], (int)bidx_s[w][spb][kk]);
                            kk += 2;
                            while (jj < na && kk >= nb2) { kk -= nb2; ++jj; }
                        }
                    }
                    float other = __shfl(acc, lane32 + 32);
                    if (lane < 32) aev_s[w][64 + pidx * 32 + lane32] = acc + other;
                }
            }
        }
        __syncthreads();

        // ---- phase B, layer 1: 384 -> 160  (320 thr: output o x atom-half h) ----
        if (t < 320) {
            const int h  = (t >= 160) ? 1 : 0;
            const int o  = t - h * 160;
            const int mb = h * 4;
            const float* Wp = W1s + o;
            float acc[4] = {0.f, 0.f, 0.f, 0.f};
            float wa[4], wb[4];
            #pragma unroll
            for (int j = 0; j < 4; ++j) wa[j] = Wp[j * 160];
            for (int f = 0; f < FAEV; f += 8) {
                const int fb = f + 4;
                #pragma unroll
                for (int j = 0; j < 4; ++j) wb[j] = Wp[(fb + j) * 160];
                #pragma unroll
                for (int m = 0; m < 4; ++m) {
                    float4 av = *(const float4*)&aev_s[mb + m][f];
                    acc[m] += av.x * wa[0] + av.y * wa[1] + av.z * wa[2] + av.w * wa[3];
                }
                const int fa = (f + 8 < FAEV) ? f + 8 : 0;
                #pragma unroll
                for (int j = 0; j < 4; ++j) wa[j] = Wp[(fa + j) * 160];
                #pragma unroll
                for (int m = 0; m < 4; ++m) {
                    float4 av = *(const float4*)&aev_s[mb + m][fb];
                    acc[m] += av.x * wb[0] + av.y * wb[1] + av.z * wb[2] + av.w * wb[3];
                }
            }
            float bb = b1s[o];
            #pragma unroll
            for (int m = 0; m < 4; ++m) {
                float x = acc[m] + bb;
                h1_s[mb + m][o] = (x > 0.f) ? x : 0.1f * (__expf(10.f * x) - 1.f);
            }
        }
        __syncthreads();   // aev_s dead -> h2/h3 overlay

        // ---- layer 2: 160 -> 128  (256 thr) ----
        if (t < 256) {
            const int h  = t >> 7;
            const int o  = t & 127;
            const int mb = h * 4;
            const float* Wp = W2s + o;
            float acc[4] = {0.f, 0.f, 0.f, 0.f};
            float wa[4], wb[4];
            #pragma unroll
            for (int j = 0; j < 4; ++j) wa[j] = Wp[j * 128];
            for (int f = 0; f < 160; f += 8) {
                const int fb = f + 4;
                #pragma unroll
                for (int j = 0; j < 4; ++j) wb[j] = Wp[(fb + j) * 128];
                #pragma unroll
                for (int m = 0; m < 4; ++m) {
                    float4 av = *(const float4*)&h1_s[mb + m][f];
                    acc[m] += av.x * wa[0] + av.y * wa[1] + av.z * wa[2] + av.w * wa[3];
                }
                const int fa = (f + 8 < 160) ? f + 8 : 0;
                #pragma unroll
                for (int j = 0; j < 4; ++j) wa[j] = Wp[(fa + j) * 128];
                #pragma unroll
                for (int m = 0; m < 4; ++m) {
                    float4 av = *(const float4*)&h1_s[mb + m][fb];
                    acc[m] += av.x * wb[0] + av.y * wb[1] + av.z * wb[2] + av.w * wb[3];
                }
            }
            float bb = b2s[o];
            #pragma unroll
            for (int m = 0; m < 4; ++m) {
                float x = acc[m] + bb;
                h2_s[mb + m][o] = (x > 0.f) ? x : 0.1f * (__expf(10.f * x) - 1.f);
            }
        }
        __syncthreads();

        // ---- layer 3: 128 -> 96  (192 thr) ----
        if (t < 192) {
            const int h  = (t >= 96) ? 1 : 0;
            const int o  = t - h * 96;
            const int mb = h * 4;
            const float* Wp = W3s + o;
            float acc[4] = {0.f, 0.f, 0.f, 0.f};
            float wa[4], wb[4];
            #pragma unroll
            for (int j = 0; j < 4; ++j) wa[j] = Wp[j * 96];
            for (int f = 0; f < 128; f += 8) {
                const int fb = f + 4;
                #pragma unroll
                for (int j = 0; j < 4; ++j) wb[j] = Wp[(fb + j) * 96];
                #pragma unroll
                for (int m = 0; m < 4; ++m) {
                    float4 av = *(const float4*)&h2_s[mb + m][f];
                    acc[m] += av.x * wa[0] + av.y * wa[1] + av.z * wa[2] + av.w * wa[3];
                }
                const int fa = (f + 8 < 128) ? f + 8 : 0;
                #pragma unroll
                for (int j = 0; j < 4; ++j) wa[j] = Wp[(fa + j) * 96];
                #pragma unroll
                for (int m = 0; m < 4; ++m) {
                    float4 av = *(const float4*)&h2_s[mb + m][fb];
                    acc[m] += av.x * wb[0] + av.y * wb[1] + av.z * wb[2] + av.w * wb[3];
                }
            }
            float bb = b3s[o];
            #pragma unroll
            for (int m = 0; m < 4; ++m) {
                float x = acc[m] + bb;
                h3_s[mb + m][o] = (x > 0.f) ? x : 0.1f * (__expf(10.f * x) - 1.f);
            }
        }
        __syncthreads();

        // ---- layer 4: 96 -> 1  (256 thr: 8 rows x 32 lanes) ----
        if (t < 256) {
            int m = t >> 5, l = t & 31;
            int a = atom_sh[m];
            if (a >= 0) {
                float p = h3_s[m][l]      * W4s[l]
                        + h3_s[m][l + 32] * W4s[l + 32]
                        + h3_s[m][l + 64] * W4s[l + 64];
                #pragma unroll
                for (int off = 16; off >= 1; off >>= 1)
                    p += __shfl_xor(p, off, 32);
                if (l == 0) atomicAdd(&out[a >> 6], p + bb4);
            }
        }
        __syncthreads();   // protect LDS + atom_sh before next tile
    }
}

extern "C" void kernel_launch(void* const* d_in, const int* in_sizes, int n_in,
                              void* d_out, int out_size, void* d_ws, size_t ws_size,
                              hipStream_t stream) {
    const int*   element_idxs  = (const int*)d_in[0];
    const int*   neighbor_idxs = (const int*)d_in[1];
    const float* distances     = (const float*)d_in[2];
    const float* diff_vectors  = (const float*)d_in[3];
    const float* W1 = (const float*)d_in[4];
    const float* b1 = (const float*)d_in[5];
    const float* W2 = (const float*)d_in[6];
    const float* b2 = (const float*)d_in[7];
    const float* W3 = (const float*)d_in[8];
    const float* b3 = (const float*)d_in[9];
    const float* W4 = (const float*)d_in[10];
    const float* b4 = (const float*)d_in[11];
    float* out = (float*)d_out;

    // workspace layout
    int* cnt   = (int*)d_ws;            // 4 ints
    int* glist = cnt + 4;               // 4*8192 ints

    hipLaunchKernelGGL(setup_kernel, dim3(1), dim3(1024), 0, stream,
                       element_idxs, cnt, glist, out);
    hipLaunchKernelGGL(fused_kernel, dim3(S_ * 256), dim3(512), 0, stream,
                       element_idxs, neighbor_idxs, distances, diff_vectors,
                       cnt, glist,
                       W1, b1, W2, b2, W3, b3, W4, b4, out);
}

// Round 12
// 259.647 us; speedup vs baseline: 1.0543x; 1.0543x over previous
//
#include <hip/hip_runtime.h>
#include <math.h>

// Problem constants
constexpr int C_ = 128, A_ = 64, K_ = 24, S_ = 4;
constexpr int NATOM = C_ * A_;    // 8192
constexpr int FAEV = 384;         // 64 radial + 320 angular
constexpr float RCR = 5.2f, RCA = 3.5f;
constexpr float PI_F = 3.14159265358979323846f;
// exp folded to exp2: exp(-eta*x^2) = exp2(K * x^2)
constexpr float K_A2 = -8.0f  * 1.44269504f;          // angular, on (hs - shfa)^2
constexpr float K_R2 = -64.0f * 1.44269504f;          // radial, on (d/2 - shfr/2)^2
constexpr float SQRT095 = 0.974679434f;               // sqrt(0.95) folded into unit vectors
constexpr float SQRT2   = 1.41421356237f;             // folded into fca (gives the 2* factor)

// ---------------- kernel 1: setup — species-sorted atom list + zero out ----------------
__global__ __launch_bounds__(1024) void setup_kernel(const int* __restrict__ elem,
                                                     int* __restrict__ cnt,
                                                     int* __restrict__ glist,
                                                     float* __restrict__ out) {
    __shared__ int cnt_s[S_];
    const int t = threadIdx.x;
    const int lane = t & 63;
    if (t < S_) cnt_s[t] = 0;
    if (t < C_) out[t] = 0.0f;
    __syncthreads();
    for (int a = t; a < NATOM; a += 1024) {
        int sp = elem[a];
        unsigned long long lt = (lane == 0) ? 0ULL : ((~0ULL) >> (64 - lane));
        int pos = 0;
        #pragma unroll
        for (int q = 0; q < S_; ++q) {
            unsigned long long m = __ballot(sp == q);
            int cw = (int)__popcll(m);
            int b = 0;
            if (lane == 0 && cw) b = atomicAdd(&cnt_s[q], cw);
            b = __shfl(b, 0);
            if (sp == q) pos = b + (int)__popcll(m & lt);
        }
        glist[sp * NATOM + pos] = a;
    }
    __syncthreads();
    if (t < S_) cnt[t] = cnt_s[t];
}

// ---------------- kernel 2: fused AEV + MLP ----------------
// 1024 blocks x 512 threads. Block = 8 same-species atoms (from glist).
// Phase A: wave w computes atom w's AEV into LDS. Phase B: MLP from LDS.
// launch_bounds (512,4): 128-VGPR budget -> NO spills (R10's (512,8) forced 32 VGPR
// and 82 MB/dispatch of scratch traffic).
__global__ __launch_bounds__(512, 4) void fused_kernel(const int* __restrict__ elem,
                                                       const int* __restrict__ nbr,
                                                       const float* __restrict__ dist,
                                                       const float* __restrict__ dv,
                                                       const int* __restrict__ cnt,
                                                       const int* __restrict__ glist,
                                                       const float* __restrict__ W1, const float* __restrict__ b1,
                                                       const float* __restrict__ W2, const float* __restrict__ b2,
                                                       const float* __restrict__ W3, const float* __restrict__ b3,
                                                       const float* __restrict__ W4, const float* __restrict__ b4,
                                                       float* __restrict__ out) {
    const int s     = blockIdx.x >> 8;          // species (4 x 256 blocks)
    const int tile0 = blockIdx.x & 255;
    const int t     = threadIdx.x;
    const int w     = t >> 6;                   // wave = atom slot 0..7
    const int lane  = t & 63;
    const int cntS  = cnt[s];

    __shared__ float4        u4_s[8][K_];       // {ux*q, uy*q, uz*q, d/2}, q = sqrt(0.95)/d
    __shared__ float         fcr_s[8][K_];
    __shared__ float         fca_s[8][K_];      // premultiplied by sqrt(2)
    __shared__ int           spec_s[8][K_];
    __shared__ unsigned char bidx_s[8][S_][K_];
    __shared__ int           nsp_s[8][S_];
    __shared__ int           atom_sh[8];
    __shared__ __attribute__((aligned(16))) float aev_s[8][FAEV];  // overlays h2(8x128)+h3(8x96)
    __shared__ __attribute__((aligned(16))) float h1_s[8][160];
    float (*h2_s)[128] = (float(*)[128])&aev_s[0][0];
    float (*h3_s)[96]  = (float(*)[96])(&aev_s[0][0] + 8 * 128);

    const float* W1s = W1 + s * (FAEV * 160);
    const float* b1s = b1 + s * 160;
    const float* W2s = W2 + s * (160 * 128);
    const float* b2s = b2 + s * 128;
    const float* W3s = W3 + s * (128 * 96);
    const float* b3s = b3 + s * 96;
    const float* W4s = W4 + s * 96;
    const float  bb4 = b4[s];

    // per-lane angular constants
    const int lane32 = lane & 31;
    const int par    = lane >> 5;
    const int zz = lane32 >> 2, yy = lane32 & 3;
    const float cz2 = 0.5f * __cosf(((float)zz + 0.5f) * (PI_F / 8.0f));
    const float sz2 = 0.5f * __sinf(((float)zz + 0.5f) * (PI_F / 8.0f));
    const float shfa_l = 0.9f + 0.65f * (float)yy;

    for (int tile = tile0; tile * 8 < cntS; tile += 256) {
        const int g = tile * 8 + w;
        const int atomAbs = (g < cntS) ? glist[s * NATOM + g] : -1;
        if (lane == 0) atom_sh[w] = atomAbs;

        // ---- phase A1: neighbor load + precompute (lanes 0..23 of each wave) ----
        if (atomAbs >= 0 && lane < K_) {
            int base = atomAbs * K_ + lane;
            int c    = atomAbs >> 6;
            int nb   = nbr[base];
            float d  = dist[base];
            float inv = __builtin_amdgcn_rcpf(d) * SQRT095;
            float4 u;
            u.x = dv[base * 3 + 0] * inv;
            u.y = dv[base * 3 + 1] * inv;
            u.z = dv[base * 3 + 2] * inv;
            u.w = 0.5f * d;
            u4_s[w][lane]  = u;
            spec_s[w][lane] = elem[(c << 6) + nb];
            fcr_s[w][lane] = (d < RCR) ? (0.5f * __cosf(PI_F * d * (1.0f / RCR)) + 0.5f) : 0.0f;
            fca_s[w][lane] = (d < RCA) ? (SQRT2 * (0.5f * __cosf(PI_F * d * (1.0f / RCA)) + 0.5f)) : 0.0f;
        }
        __syncthreads();

        // ---- phase A2: bucket active neighbors by species (lanes 0..3 of each wave) ----
        if (atomAbs >= 0 && lane < S_) {
            int n = 0;
            #pragma unroll
            for (int k = 0; k < K_; ++k)
                if (fca_s[w][k] > 0.0f && spec_s[w][k] == lane)
                    bidx_s[w][lane][n++] = (unsigned char)k;
            nsp_s[w][lane] = n;
        }
        __syncthreads();

        // ---- phase A3: radial + angular AEV (full wave per atom) ----
        if (atomAbs >= 0) {
            // radial: lane = sp*16 + shell
            {
                const int   spg   = lane >> 4;
                const float shfrh = 0.5f * (0.9f + 0.26875f * (float)(lane & 15));
                float acc = 0.0f;
                #pragma unroll
                for (int k = 0; k < K_; ++k) {
                    float hd = u4_s[w][k].w;
                    float df = hd - shfrh;
                    float term = 0.25f * exp2f(df * df * K_R2) * fcr_s[w][k];
                    if (spec_s[w][k] == spg) acc += term;
                }
                aev_s[w][lane] = acc;
            }
            // angular: 10 species-pair segments; halves = even/odd pairs of the stream
            auto pair_term = [&](int j, int k2) -> float {
                float4 u1 = u4_s[w][j], u2 = u4_s[w][k2];
                float ca = u1.x * u2.x + u1.y * u2.y + u1.z * u2.z;   // = 0.95*cos
                float sa = sqrtf(1.0f - ca * ca);
                float dd = (u1.w + u2.w) - shfa_l;
                float f2 = exp2f(dd * dd * K_A2);
                float x  = 0.5f + ca * cz2 + sa * sz2;
                float x2 = x * x, x4 = x2 * x2, x8 = x4 * x4, x16 = x8 * x8;
                float tc = fca_s[w][j] * fca_s[w][k2];                // = 2*fc1*fc2
                return (x16 * x16) * (f2 * tc);
            };
            #pragma unroll
            for (int spa = 0; spa < 4; ++spa) {
                #pragma unroll
                for (int spb = spa; spb < 4; ++spb) {
                    const int pidx = spa * (9 - spa) / 2 + (spb - spa);
                    const int na  = nsp_s[w][spa];
                    const int nb2 = nsp_s[w][spb];
                    float acc = 0.0f;
                    if (spa == spb) {
                        int jj = 0, kk = 1 + par;
                        while (jj < na - 1 && kk >= na) { int ov = kk - na; ++jj; kk = jj + 1 + ov; }
                        while (jj < na - 1) {
                            acc += pair_term((int)bidx_s[w][spa][jj], (int)bidx_s[w][spa][kk]);
                            kk += 2;
                            while (jj < na - 1 && kk >= na) { int ov = kk - na; ++jj; kk = jj + 1 + ov; }
                        }
                    } else {
                        int jj = 0, kk = par;
                        while (jj < na && kk >= nb2) { kk -= nb2; ++jj; }
                        while (jj < na) {
                            acc += pair_term((int)bidx_s[w][spa][jj], (int)bidx_s[w][spb][kk]);
                            kk += 2;
                            while (jj < na && kk >= nb2) { kk -= nb2; ++jj; }
                        }
                    }
                    float other = __shfl(acc, lane32 + 32);
                    if (lane < 32) aev_s[w][64 + pidx * 32 + lane32] = acc + other;
                }
            }
        }
        __syncthreads();

        // ---- phase B, layer 1: 384 -> 160  (320 thr: output o x atom-half h) ----
        if (t < 320) {
            const int h  = (t >= 160) ? 1 : 0;
            const int o  = t - h * 160;
            const int mb = h * 4;
            const float* Wp = W1s + o;
            float acc[4] = {0.f, 0.f, 0.f, 0.f};
            float wa[4], wb[4];
            #pragma unroll
            for (int j = 0; j < 4; ++j) wa[j] = Wp[j * 160];
            for (int f = 0; f < FAEV; f += 8) {
                const int fb = f + 4;
                #pragma unroll
                for (int j = 0; j < 4; ++j) wb[j] = Wp[(fb + j) * 160];
                #pragma unroll
                for (int m = 0; m < 4; ++m) {
                    float4 av = *(const float4*)&aev_s[mb + m][f];
                    acc[m] += av.x * wa[0] + av.y * wa[1] + av.z * wa[2] + av.w * wa[3];
                }
                const int fa = (f + 8 < FAEV) ? f + 8 : 0;
                #pragma unroll
                for (int j = 0; j < 4; ++j) wa[j] = Wp[(fa + j) * 160];
                #pragma unroll
                for (int m = 0; m < 4; ++m) {
                    float4 av = *(const float4*)&aev_s[mb + m][fb];
                    acc[m] += av.x * wb[0] + av.y * wb[1] + av.z * wb[2] + av.w * wb[3];
                }
            }
            float bb = b1s[o];
            #pragma unroll
            for (int m = 0; m < 4; ++m) {
                float x = acc[m] + bb;
                h1_s[mb + m][o] = (x > 0.f) ? x : 0.1f * (__expf(10.f * x) - 1.f);
            }
        }
        __syncthreads();   // aev_s dead -> h2/h3 overlay

        // ---- layer 2: 160 -> 128  (256 thr) ----
        if (t < 256) {
            const int h  = t >> 7;
            const int o  = t & 127;
            const int mb = h * 4;
            const float* Wp = W2s + o;
            float acc[4] = {0.f, 0.f, 0.f, 0.f};
            float wa[4], wb[4];
            #pragma unroll
            for (int j = 0; j < 4; ++j) wa[j] = Wp[j * 128];
            for (int f = 0; f < 160; f += 8) {
                const int fb = f + 4;
                #pragma unroll
                for (int j = 0; j < 4; ++j) wb[j] = Wp[(fb + j) * 128];
                #pragma unroll
                for (int m = 0; m < 4; ++m) {
                    float4 av = *(const float4*)&h1_s[mb + m][f];
                    acc[m] += av.x * wa[0] + av.y * wa[1] + av.z * wa[2] + av.w * wa[3];
                }
                const int fa = (f + 8 < 160) ? f + 8 : 0;
                #pragma unroll
                for (int j = 0; j < 4; ++j) wa[j] = Wp[(fa + j) * 128];
                #pragma unroll
                for (int m = 0; m < 4; ++m) {
                    float4 av = *(const float4*)&h1_s[mb + m][fb];
                    acc[m] += av.x * wb[0] + av.y * wb[1] + av.z * wb[2] + av.w * wb[3];
                }
            }
            float bb = b2s[o];
            #pragma unroll
            for (int m = 0; m < 4; ++m) {
                float x = acc[m] + bb;
                h2_s[mb + m][o] = (x > 0.f) ? x : 0.1f * (__expf(10.f * x) - 1.f);
            }
        }
        __syncthreads();

        // ---- layer 3: 128 -> 96  (192 thr) ----
        if (t < 192) {
            const int h  = (t >= 96) ? 1 : 0;
            const int o  = t - h * 96;
            const int mb = h * 4;
            const float* Wp = W3s + o;
            float acc[4] = {0.f, 0.f, 0.f, 0.f};
            float wa[4], wb[4];
            #pragma unroll
            for (int j = 0; j < 4; ++j) wa[j] = Wp[j * 96];
            for (int f = 0; f < 128; f += 8) {
                const int fb = f + 4;
                #pragma unroll
                for (int j = 0; j < 4; ++j) wb[j] = Wp[(fb + j) * 96];
                #pragma unroll
                for (int m = 0; m < 4; ++m) {
                    float4 av = *(const float4*)&h2_s[mb + m][f];
                    acc[m] += av.x * wa[0] + av.y * wa[1] + av.z * wa[2] + av.w * wa[3];
                }
                const int fa = (f + 8 < 128) ? f + 8 : 0;
                #pragma unroll
                for (int j = 0; j < 4; ++j) wa[j] = Wp[(fa + j) * 96];
                #pragma unroll
                for (int m = 0; m < 4; ++m) {
                    float4 av = *(const float4*)&h2_s[mb + m][fb];
                    acc[m] += av.x * wb[0] + av.y * wb[1] + av.z * wb[2] + av.w * wb[3];
                }
            }
            float bb = b3s[o];
            #pragma unroll
            for (int m = 0; m < 4; ++m) {
                float x = acc[m] + bb;
                h3_s[mb + m][o] = (x > 0.f) ? x : 0.1f * (__expf(10.f * x) - 1.f);
            }
        }
        __syncthreads();

        // ---- layer 4: 96 -> 1  (256 thr: 8 rows x 32 lanes) ----
        if (t < 256) {
            int m = t >> 5, l = t & 31;
            int a = atom_sh[m];
            if (a >= 0) {
                float p = h3_s[m][l]      * W4s[l]
                        + h3_s[m][l + 32] * W4s[l + 32]
                        + h3_s[m][l + 64] * W4s[l + 64];
                #pragma unroll
                for (int off = 16; off >= 1; off >>= 1)
                    p += __shfl_xor(p, off, 32);
                if (l == 0) atomicAdd(&out[a >> 6], p + bb4);
            }
        }
        __syncthreads();   // protect LDS + atom_sh before next tile
    }
}

extern "C" void kernel_launch(void* const* d_in, const int* in_sizes, int n_in,
                              void* d_out, int out_size, void* d_ws, size_t ws_size,
                              hipStream_t stream) {
    const int*   element_idxs  = (const int*)d_in[0];
    const int*   neighbor_idxs = (const int*)d_in[1];
    const float* distances     = (const float*)d_in[2];
    const float* diff_vectors  = (const float*)d_in[3];
    const float* W1 = (const float*)d_in[4];
    const float* b1 = (const float*)d_in[5];
    const float* W2 = (const float*)d_in[6];
    const float* b2 = (const float*)d_in[7];
    const float* W3 = (const float*)d_in[8];
    const float* b3 = (const float*)d_in[9];
    const float* W4 = (const float*)d_in[10];
    const float* b4 = (const float*)d_in[11];
    float* out = (float*)d_out;

    // workspace layout
    int* cnt   = (int*)d_ws;            // 4 ints
    int* glist = cnt + 4;               // 4*8192 ints

    hipLaunchKernelGGL(setup_kernel, dim3(1), dim3(1024), 0, stream,
                       element_idxs, cnt, glist, out);
    hipLaunchKernelGGL(fused_kernel, dim3(S_ * 256), dim3(512), 0, stream,
                       element_idxs, neighbor_idxs, distances, diff_vectors,
                       cnt, glist,
                       W1, b1, W2, b2, W3, b3, W4, b4, out);
}

// Round 13
// 231.922 us; speedup vs baseline: 1.1803x; 1.1195x over previous
//
#include <hip/hip_runtime.h>
#include <math.h>

// Problem constants
constexpr int C_ = 128, A_ = 64, K_ = 24, S_ = 4;
constexpr int NATOM = C_ * A_;    // 8192
constexpr int FAEV = 384;         // 64 radial + 320 angular
constexpr float RCR = 5.2f, RCA = 3.5f;
constexpr float PI_F = 3.14159265358979323846f;
// exp folded to exp2: exp(-eta*x^2) = exp2(K * x^2)
constexpr float K_A2 = -8.0f  * 1.44269504f;          // angular, on (hs - shfa)^2
constexpr float K_R2 = -64.0f * 1.44269504f;          // radial, on (d/2 - shfr/2)^2
constexpr float SQRT095 = 0.974679434f;               // sqrt(0.95) folded into unit vectors
constexpr float SQRT2   = 1.41421356237f;             // folded into fca (gives the 2* factor)

// ---------------- kernel 1: setup — species-sorted atom list + zero out ----------------
__global__ __launch_bounds__(1024) void setup_kernel(const int* __restrict__ elem,
                                                     int* __restrict__ cnt,
                                                     int* __restrict__ glist,
                                                     float* __restrict__ out) {
    __shared__ int cnt_s[S_];
    const int t = threadIdx.x;
    const int lane = t & 63;
    if (t < S_) cnt_s[t] = 0;
    if (t < C_) out[t] = 0.0f;
    __syncthreads();
    for (int a = t; a < NATOM; a += 1024) {
        int sp = elem[a];
        unsigned long long lt = (lane == 0) ? 0ULL : ((~0ULL) >> (64 - lane));
        int pos = 0;
        #pragma unroll
        for (int q = 0; q < S_; ++q) {
            unsigned long long m = __ballot(sp == q);
            int cw = (int)__popcll(m);
            int b = 0;
            if (lane == 0 && cw) b = atomicAdd(&cnt_s[q], cw);
            b = __shfl(b, 0);
            if (sp == q) pos = b + (int)__popcll(m & lt);
        }
        glist[sp * NATOM + pos] = a;
    }
    __syncthreads();
    if (t < S_) cnt[t] = cnt_s[t];
}

// ---------------- kernel 2: fused AEV + MLP ----------------
// 1024 blocks x 512 threads. Block = 8 same-species atoms (from glist).
// Phase A: wave w computes atom w's AEV into LDS (wave-private: NO barriers inside A).
// Angular pairs iterated by flat index with closed-form decode -> independent
// iterations the compiler can pipeline (old version had a loop-carried
// stream-advance chain that serialized every LDS read).
__global__ __launch_bounds__(512, 4) void fused_kernel(const int* __restrict__ elem,
                                                       const int* __restrict__ nbr,
                                                       const float* __restrict__ dist,
                                                       const float* __restrict__ dv,
                                                       const int* __restrict__ cnt,
                                                       const int* __restrict__ glist,
                                                       const float* __restrict__ W1, const float* __restrict__ b1,
                                                       const float* __restrict__ W2, const float* __restrict__ b2,
                                                       const float* __restrict__ W3, const float* __restrict__ b3,
                                                       const float* __restrict__ W4, const float* __restrict__ b4,
                                                       float* __restrict__ out) {
    const int s     = blockIdx.x >> 8;          // species (4 x 256 blocks)
    const int tile0 = blockIdx.x & 255;
    const int t     = threadIdx.x;
    const int w     = t >> 6;                   // wave = atom slot 0..7
    const int lane  = t & 63;
    const int cntS  = cnt[s];

    __shared__ float4        u4_s[8][K_];       // {ux*q, uy*q, uz*q, d/2}, q = sqrt(0.95)/d
    __shared__ float         fcr_s[8][K_];
    __shared__ float         fca_s[8][K_];      // premultiplied by sqrt(2)
    __shared__ int           spec_s[8][K_];
    __shared__ unsigned char bidx_s[8][S_][K_];
    __shared__ int           atom_sh[8];
    __shared__ __attribute__((aligned(16))) float aev_s[8][FAEV];  // overlays h2(8x128)+h3(8x96)
    __shared__ __attribute__((aligned(16))) float h1_s[8][160];
    float (*h2_s)[128] = (float(*)[128])&aev_s[0][0];
    float (*h3_s)[96]  = (float(*)[96])(&aev_s[0][0] + 8 * 128);

    const float* W1s = W1 + s * (FAEV * 160);
    const float* b1s = b1 + s * 160;
    const float* W2s = W2 + s * (160 * 128);
    const float* b2s = b2 + s * 128;
    const float* W3s = W3 + s * (128 * 96);
    const float* b3s = b3 + s * 96;
    const float* W4s = W4 + s * 96;
    const float  bb4 = b4[s];

    // per-lane angular constants
    const int lane32 = lane & 31;
    const int par    = lane >> 5;
    const int zz = lane32 >> 2, yy = lane32 & 3;
    const float cz2 = 0.5f * __cosf(((float)zz + 0.5f) * (PI_F / 8.0f));
    const float sz2 = 0.5f * __sinf(((float)zz + 0.5f) * (PI_F / 8.0f));
    const float shfa_l = 0.9f + 0.65f * (float)yy;
    const unsigned long long ltmask = (lane == 0) ? 0ULL : ((~0ULL) >> (64 - lane));

    for (int tile = tile0; tile * 8 < cntS; tile += 256) {
        const int g = tile * 8 + w;
        const int atomAbs = (g < cntS) ? glist[s * NATOM + g] : -1;
        if (lane == 0) atom_sh[w] = atomAbs;

        // ---- phase A1: neighbor load + precompute (lanes 0..23; wave-private LDS) ----
        int   mySpec = -1;
        float myFca  = 0.0f;
        if (atomAbs >= 0 && lane < K_) {
            int base = atomAbs * K_ + lane;
            int c    = atomAbs >> 6;
            int nb   = nbr[base];
            float d  = dist[base];
            float inv = __builtin_amdgcn_rcpf(d) * SQRT095;
            float4 u;
            u.x = dv[base * 3 + 0] * inv;
            u.y = dv[base * 3 + 1] * inv;
            u.z = dv[base * 3 + 2] * inv;
            u.w = 0.5f * d;
            u4_s[w][lane]  = u;
            mySpec = elem[(c << 6) + nb];
            spec_s[w][lane] = mySpec;
            fcr_s[w][lane] = (d < RCR) ? (0.5f * __cosf(PI_F * d * (1.0f / RCR)) + 0.5f) : 0.0f;
            myFca = (d < RCA) ? (SQRT2 * (0.5f * __cosf(PI_F * d * (1.0f / RCA)) + 0.5f)) : 0.0f;
            fca_s[w][lane] = myFca;
        }

        // ---- phase A2: ballot-parallel species bucket build (no barrier; wave-private) ----
        int nspR[S_];
        {
            const bool act = (myFca > 0.0f);   // implies lane<K_ and atomAbs>=0
            #pragma unroll
            for (int q = 0; q < S_; ++q) {
                unsigned long long mk = __ballot(act && (mySpec == q));
                if (act && (mySpec == q))
                    bidx_s[w][q][(int)__popcll(mk & ltmask)] = (unsigned char)lane;
                nspR[q] = (int)__popcll(mk);
            }
        }

        // ---- phase A3: radial + angular AEV (full wave per atom; wave-private) ----
        if (atomAbs >= 0) {
            // radial: lane = sp*16 + shell
            {
                const int   spg   = lane >> 4;
                const float shfrh = 0.5f * (0.9f + 0.26875f * (float)(lane & 15));
                float acc = 0.0f;
                #pragma unroll
                for (int k = 0; k < K_; ++k) {
                    float hd = u4_s[w][k].w;
                    float df = hd - shfrh;
                    float term = 0.25f * exp2f(df * df * K_R2) * fcr_s[w][k];
                    if (spec_s[w][k] == spg) acc += term;
                }
                aev_s[w][lane] = acc;
            }
            // angular: 10 species-pair segments, flat pair index + closed-form decode
            auto pair_term = [&](int j, int k2) -> float {
                float4 u1 = u4_s[w][j], u2 = u4_s[w][k2];
                float ca = u1.x * u2.x + u1.y * u2.y + u1.z * u2.z;   // = 0.95*cos
                float sa = __builtin_amdgcn_sqrtf(1.0f - ca * ca);    // >= 0.097, safe
                float dd = (u1.w + u2.w) - shfa_l;
                float f2 = exp2f(dd * dd * K_A2);
                float x  = 0.5f + ca * cz2 + sa * sz2;
                float x2 = x * x, x4 = x2 * x2, x8 = x4 * x4, x16 = x8 * x8;
                float tc = fca_s[w][j] * fca_s[w][k2];                // = 2*fc1*fc2
                return (x16 * x16) * (f2 * tc);
            };
            #pragma unroll
            for (int spa = 0; spa < 4; ++spa) {
                #pragma unroll
                for (int spb = spa; spb < 4; ++spb) {
                    const int pidx = spa * (9 - spa) / 2 + (spb - spa);
                    const int na = nspR[spa];
                    float acc = 0.0f;
                    if (spa == spb) {
                        // triangular: q-th pair (i<j) of na actives
                        const int   T   = (na * (na - 1)) >> 1;
                        const float ff  = (float)(2 * na - 1);
                        const float ff2 = ff * ff;
                        for (int q = par; q < T; q += 2) {
                            float sq = __builtin_amdgcn_sqrtf(ff2 - 8.0f * (float)q);
                            int i = (int)((ff - sq) * 0.5f);
                            int st1 = (i + 1) * (na - 1) - (((i + 1) * i) >> 1);
                            if (st1 <= q) ++i;
                            int st = i * (na - 1) - ((i * (i - 1)) >> 1);
                            if (st > q) { --i; st = i * (na - 1) - ((i * (i - 1)) >> 1); }
                            int j2 = q - st + i + 1;
                            acc += pair_term((int)bidx_s[w][spa][i], (int)bidx_s[w][spa][j2]);
                        }
                    } else {
                        // rectangular: q = i*nb2 + j
                        const int   nb2 = nspR[spb];
                        const int   T   = na * nb2;
                        const float rcp = __builtin_amdgcn_rcpf((float)nb2);
                        for (int q = par; q < T; q += 2) {
                            int i  = (int)(((float)q + 0.5f) * rcp);
                            int j2 = q - i * nb2;
                            acc += pair_term((int)bidx_s[w][spa][i], (int)bidx_s[w][spb][j2]);
                        }
                    }
                    float other = __shfl(acc, lane32 + 32);
                    if (lane < 32) aev_s[w][64 + pidx * 32 + lane32] = acc + other;
                }
            }
        }
        __syncthreads();   // AEV of all 8 atoms ready -> cross-wave MLP

        // ---- phase B, layer 1: 384 -> 160  (320 thr: output o x atom-half h) ----
        if (t < 320) {
            const int h  = (t >= 160) ? 1 : 0;
            const int o  = t - h * 160;
            const int mb = h * 4;
            const float* Wp = W1s + o;
            float acc[4] = {0.f, 0.f, 0.f, 0.f};
            float wa[4], wb[4];
            #pragma unroll
            for (int j = 0; j < 4; ++j) wa[j] = Wp[j * 160];
            for (int f = 0; f < FAEV; f += 8) {
                const int fb = f + 4;
                #pragma unroll
                for (int j = 0; j < 4; ++j) wb[j] = Wp[(fb + j) * 160];
                #pragma unroll
                for (int m = 0; m < 4; ++m) {
                    float4 av = *(const float4*)&aev_s[mb + m][f];
                    acc[m] += av.x * wa[0] + av.y * wa[1] + av.z * wa[2] + av.w * wa[3];
                }
                const int fa = (f + 8 < FAEV) ? f + 8 : 0;
                #pragma unroll
                for (int j = 0; j < 4; ++j) wa[j] = Wp[(fa + j) * 160];
                #pragma unroll
                for (int m = 0; m < 4; ++m) {
                    float4 av = *(const float4*)&aev_s[mb + m][fb];
                    acc[m] += av.x * wb[0] + av.y * wb[1] + av.z * wb[2] + av.w * wb[3];
                }
            }
            float bb = b1s[o];
            #pragma unroll
            for (int m = 0; m < 4; ++m) {
                float x = acc[m] + bb;
                h1_s[mb + m][o] = (x > 0.f) ? x : 0.1f * (__expf(10.f * x) - 1.f);
            }
        }
        __syncthreads();   // aev_s dead -> h2/h3 overlay

        // ---- layer 2: 160 -> 128  (256 thr) ----
        if (t < 256) {
            const int h  = t >> 7;
            const int o  = t & 127;
            const int mb = h * 4;
            const float* Wp = W2s + o;
            float acc[4] = {0.f, 0.f, 0.f, 0.f};
            float wa[4], wb[4];
            #pragma unroll
            for (int j = 0; j < 4; ++j) wa[j] = Wp[j * 128];
            for (int f = 0; f < 160; f += 8) {
                const int fb = f + 4;
                #pragma unroll
                for (int j = 0; j < 4; ++j) wb[j] = Wp[(fb + j) * 128];
                #pragma unroll
                for (int m = 0; m < 4; ++m) {
                    float4 av = *(const float4*)&h1_s[mb + m][f];
                    acc[m] += av.x * wa[0] + av.y * wa[1] + av.z * wa[2] + av.w * wa[3];
                }
                const int fa = (f + 8 < 160) ? f + 8 : 0;
                #pragma unroll
                for (int j = 0; j < 4; ++j) wa[j] = Wp[(fa + j) * 128];
                #pragma unroll
                for (int m = 0; m < 4; ++m) {
                    float4 av = *(const float4*)&h1_s[mb + m][fb];
                    acc[m] += av.x * wb[0] + av.y * wb[1] + av.z * wb[2] + av.w * wb[3];
                }
            }
            float bb = b2s[o];
            #pragma unroll
            for (int m = 0; m < 4; ++m) {
                float x = acc[m] + bb;
                h2_s[mb + m][o] = (x > 0.f) ? x : 0.1f * (__expf(10.f * x) - 1.f);
            }
        }
        __syncthreads();

        // ---- layer 3: 128 -> 96  (192 thr) ----
        if (t < 192) {
            const int h  = (t >= 96) ? 1 : 0;
            const int o  = t - h * 96;
            const int mb = h * 4;
            const float* Wp = W3s + o;
            float acc[4] = {0.f, 0.f, 0.f, 0.f};
            float wa[4], wb[4];
            #pragma unroll
            for (int j = 0; j < 4; ++j) wa[j] = Wp[j * 96];
            for (int f = 0; f < 128; f += 8) {
                const int fb = f + 4;
                #pragma unroll
                for (int j = 0; j < 4; ++j) wb[j] = Wp[(fb + j) * 96];
                #pragma unroll
                for (int m = 0; m < 4; ++m) {
                    float4 av = *(const float4*)&h2_s[mb + m][f];
                    acc[m] += av.x * wa[0] + av.y * wa[1] + av.z * wa[2] + av.w * wa[3];
                }
                const int fa = (f + 8 < 128) ? f + 8 : 0;
                #pragma unroll
                for (int j = 0; j < 4; ++j) wa[j] = Wp[(fa + j) * 96];
                #pragma unroll
                for (int m = 0; m < 4; ++m) {
                    float4 av = *(const float4*)&h2_s[mb + m][fb];
                    acc[m] += av.x * wb[0] + av.y * wb[1] + av.z * wb[2] + av.w * wb[3];
                }
            }
            float bb = b3s[o];
            #pragma unroll
            for (int m = 0; m < 4; ++m) {
                float x = acc[m] + bb;
                h3_s[mb + m][o] = (x > 0.f) ? x : 0.1f * (__expf(10.f * x) - 1.f);
            }
        }
        __syncthreads();

        // ---- layer 4: 96 -> 1  (256 thr: 8 rows x 32 lanes) ----
        if (t < 256) {
            int m = t >> 5, l = t & 31;
            int a = atom_sh[m];
            if (a >= 0) {
                float p = h3_s[m][l]      * W4s[l]
                        + h3_s[m][l + 32] * W4s[l + 32]
                        + h3_s[m][l + 64] * W4s[l + 64];
                #pragma unroll
                for (int off = 16; off >= 1; off >>= 1)
                    p += __shfl_xor(p, off, 32);
                if (l == 0) atomicAdd(&out[a >> 6], p + bb4);
            }
        }
        __syncthreads();   // protect LDS + atom_sh before next tile
    }
}

extern "C" void kernel_launch(void* const* d_in, const int* in_sizes, int n_in,
                              void* d_out, int out_size, void* d_ws, size_t ws_size,
                              hipStream_t stream) {
    const int*   element_idxs  = (const int*)d_in[0];
    const int*   neighbor_idxs = (const int*)d_in[1];
    const float* distances     = (const float*)d_in[2];
    const float* diff_vectors  = (const float*)d_in[3];
    const float* W1 = (const float*)d_in[4];
    const float* b1 = (const float*)d_in[5];
    const float* W2 = (const float*)d_in[6];
    const float* b2 = (const float*)d_in[7];
    const float* W3 = (const float*)d_in[8];
    const float* b3 = (const float*)d_in[9];
    const float* W4 = (const float*)d_in[10];
    const float* b4 = (const float*)d_in[11];
    float* out = (float*)d_out;

    // workspace layout
    int* cnt   = (int*)d_ws;            // 4 ints
    int* glist = cnt + 4;               // 4*8192 ints

    hipLaunchKernelGGL(setup_kernel, dim3(1), dim3(1024), 0, stream,
                       element_idxs, cnt, glist, out);
    hipLaunchKernelGGL(fused_kernel, dim3(S_ * 256), dim3(512), 0, stream,
                       element_idxs, neighbor_idxs, distances, diff_vectors,
                       cnt, glist,
                       W1, b1, W2, b2, W3, b3, W4, b4, out);
}